// Round 1
// baseline (3815.463 us; speedup 1.0000x reference)
//
#include <hip/hip_runtime.h>
#include <math.h>

#define NB 1024
#define NT 64
#define NA 6
#define NS 30
#define ND 200
#define NH 200
#define NE 1024
#define OC 580
#define R 4
#define PG 32

__device__ __forceinline__ float elu_f(float x) { return x > 0.f ? x : __expf(x) - 1.f; }
__device__ __forceinline__ float sig_f(float x) { return 1.f / (1.f + __expf(-x)); }
__device__ __forceinline__ float sp_f(float x)  { return x > 20.f ? x : log1pf(__expf(x)); }

// acc[r] += dot(w[0:200], src[r][0:200]); w rows consumed in 32B chunks.
__device__ __forceinline__ void rowdot(const float* __restrict__ w,
                                       const float (*__restrict__ src)[200],
                                       float acc[R])
{
    for (int k0 = 0; k0 < 200; k0 += 8) {
        const float4 w0 = *reinterpret_cast<const float4*>(&w[k0]);
        const float4 w1 = *reinterpret_cast<const float4*>(&w[k0 + 4]);
        #pragma unroll
        for (int r = 0; r < R; ++r) {
            const float4 s0 = *reinterpret_cast<const float4*>(&src[r][k0]);
            const float4 s1 = *reinterpret_cast<const float4*>(&src[r][k0 + 4]);
            acc[r] += w0.x * s0.x + w0.y * s0.y + w0.z * s0.z + w0.w * s0.w
                    + w1.x * s1.x + w1.y * s1.y + w1.z * s1.z + w1.w * s1.w;
        }
    }
}

// ---------------------------------------------------------------------------
// Epre[bt][j] = embed[bt][:] . Wq1[j][200:1224] + bq1[j], stashed at
// out[bt*580 + 290 + j] (j<200).  BM=64 rows/block, BK=16, 256 thr (16x16),
// each thread: 4 rows x 13 cols.
// ---------------------------------------------------------------------------
__global__ __launch_bounds__(256) void epre_kernel(
    const float* __restrict__ embed, const float* __restrict__ Wq1,
    const float* __restrict__ bq1, float* __restrict__ out)
{
    __shared__ float s_a[16][68];   // [k][i], padded
    __shared__ float s_w[200][17];  // [j][k], padded
    const int tid = threadIdx.x;
    const int tx = tid & 15, ty = tid >> 4;
    const int bt0 = blockIdx.x * 64;
    float acc[4][13];
    #pragma unroll
    for (int r = 0; r < 4; ++r)
        #pragma unroll
        for (int c = 0; c < 13; ++c) acc[r][c] = 0.f;

    for (int k0 = 0; k0 < NE; k0 += 16) {
        {   // stage A tile: one float4 per thread, coalesced 64B per 4 lanes
            const int i = tid >> 2, kq = (tid & 3) * 4;
            const float4 v = *reinterpret_cast<const float4*>(
                &embed[(size_t)(bt0 + i) * NE + k0 + kq]);
            s_a[kq + 0][i] = v.x; s_a[kq + 1][i] = v.y;
            s_a[kq + 2][i] = v.z; s_a[kq + 3][i] = v.w;
        }
        for (int idx = tid; idx < 800; idx += 256) {  // stage W tile
            const int j = idx >> 2, kq = (idx & 3) * 4;
            const float4 v = *reinterpret_cast<const float4*>(
                &Wq1[(size_t)j * 1224 + 200 + k0 + kq]);
            s_w[j][kq + 0] = v.x; s_w[j][kq + 1] = v.y;
            s_w[j][kq + 2] = v.z; s_w[j][kq + 3] = v.w;
        }
        __syncthreads();
        #pragma unroll
        for (int kk = 0; kk < 16; ++kk) {
            const float4 a4 = *reinterpret_cast<const float4*>(&s_a[kk][ty * 4]);
            #pragma unroll
            for (int c = 0; c < 12; ++c) {
                const float w = s_w[tx + 16 * c][kk];
                acc[0][c] += a4.x * w; acc[1][c] += a4.y * w;
                acc[2][c] += a4.z * w; acc[3][c] += a4.w * w;
            }
            if (tx < 8) {
                const float w = s_w[tx + 192][kk];
                acc[0][12] += a4.x * w; acc[1][12] += a4.y * w;
                acc[2][12] += a4.z * w; acc[3][12] += a4.w * w;
            }
        }
        __syncthreads();
    }
    #pragma unroll
    for (int r = 0; r < 4; ++r) {
        const int i = ty * 4 + r;
        #pragma unroll
        for (int c = 0; c < 12; ++c) {
            const int j = tx + 16 * c;
            out[(size_t)(bt0 + i) * OC + 290 + j] = acc[r][c] + bq1[j];
        }
        if (tx < 8)
            out[(size_t)(bt0 + i) * OC + 290 + tx + 192] = acc[r][12] + bq1[tx + 192];
    }
}

// ---------------------------------------------------------------------------
// Sequential scan: 256 blocks x 4 batch rows, t-loop inside.
// ---------------------------------------------------------------------------
__global__ __launch_bounds__(256) void scan_kernel(
    const float* __restrict__ action, const float* __restrict__ noise_post,
    const float* __restrict__ Wi, const float* __restrict__ bi,
    const float* __restrict__ W_ih, const float* __restrict__ W_hh,
    const float* __restrict__ b_ih, const float* __restrict__ b_hh,
    const float* __restrict__ Wq1, const float* __restrict__ Wq2,
    const float* __restrict__ bq2, float* __restrict__ out)
{
    __shared__ float s_in[R][36];       // [stoch(30) | action(6)]
    __shared__ float s_x[R][200];
    __shared__ float s_deter[R][200];
    __shared__ float s_dnew[R][200];
    __shared__ float s_hq[R][200];
    __shared__ float s_q[R][60];
    const int tid = threadIdx.x;
    const int b0 = blockIdx.x * R;

    for (int idx = tid; idx < R * 36; idx += 256) ((float*)s_in)[idx] = 0.f;
    for (int idx = tid; idx < R * 200; idx += 256) ((float*)s_deter)[idx] = 0.f;
    __syncthreads();

    for (int t = 0; t < NT; ++t) {
        if (tid < R * NA) {
            const int r = tid / NA, k = tid % NA;
            s_in[r][30 + k] = action[((size_t)(b0 + r) * NT + t) * NA + k];
        }
        __syncthreads();
        // phase A: x = elu([stoch, act] @ Wi^T + bi)
        if (tid < NH) {
            const int j = tid;
            float acc[R];
            #pragma unroll
            for (int r = 0; r < R; ++r) acc[r] = bi[j];
            const float* w = &Wi[(size_t)j * 36];
            #pragma unroll
            for (int q = 0; q < 9; ++q) {
                const float4 w4 = *reinterpret_cast<const float4*>(&w[q * 4]);
                #pragma unroll
                for (int r = 0; r < R; ++r) {
                    const float4 i4 = *reinterpret_cast<const float4*>(&s_in[r][q * 4]);
                    acc[r] += w4.x * i4.x + w4.y * i4.y + w4.z * i4.z + w4.w * i4.w;
                }
            }
            #pragma unroll
            for (int r = 0; r < R; ++r) s_x[r][j] = elu_f(acc[r]);
        }
        __syncthreads();
        // phase B: GRU cell -> s_dnew
        if (tid < ND) {
            const int j = tid;
            float Ar[R], Az[R], An[R], Hr[R], Hz[R], Hn[R];
            #pragma unroll
            for (int r = 0; r < R; ++r) {
                Ar[r] = b_ih[j];  Az[r] = b_ih[ND + j];  An[r] = b_ih[2 * ND + j];
                Hr[r] = b_hh[j];  Hz[r] = b_hh[ND + j];  Hn[r] = b_hh[2 * ND + j];
            }
            rowdot(&W_ih[(size_t)j * ND],            (const float (*)[200])s_x,     Ar);
            rowdot(&W_ih[(size_t)(ND + j) * ND],     (const float (*)[200])s_x,     Az);
            rowdot(&W_ih[(size_t)(2 * ND + j) * ND], (const float (*)[200])s_x,     An);
            rowdot(&W_hh[(size_t)j * ND],            (const float (*)[200])s_deter, Hr);
            rowdot(&W_hh[(size_t)(ND + j) * ND],     (const float (*)[200])s_deter, Hz);
            rowdot(&W_hh[(size_t)(2 * ND + j) * ND], (const float (*)[200])s_deter, Hn);
            #pragma unroll
            for (int r = 0; r < R; ++r) {
                const float rr = sig_f(Ar[r] + Hr[r]);
                const float zz = sig_f(Az[r] + Hz[r]);
                const float nn = tanhf(An[r] + rr * Hn[r]);
                s_dnew[r][j] = (1.f - zz) * nn + zz * s_deter[r][j];
            }
        }
        __syncthreads();
        // phase C: hq = elu(deter_new @ Wq1[:, :200]^T + Epre)
        if (tid < NH) {
            const int j = tid;
            float acc[R];
            #pragma unroll
            for (int r = 0; r < R; ++r)
                acc[r] = out[((size_t)(b0 + r) * NT + t) * OC + 290 + j];  // Epre (incl bq1)
            rowdot(&Wq1[(size_t)j * 1224], (const float (*)[200])s_dnew, acc);
            #pragma unroll
            for (int r = 0; r < R; ++r) s_hq[r][j] = elu_f(acc[r]);
        }
        __syncthreads();
        // phase D1: [qm|qs]_raw = hq @ Wq2^T + bq2
        if (tid < 60) {
            const int j = tid;
            float acc[R];
            #pragma unroll
            for (int r = 0; r < R; ++r) acc[r] = bq2[j];
            rowdot(&Wq2[(size_t)j * ND], (const float (*)[200])s_hq, acc);
            #pragma unroll
            for (int r = 0; r < R; ++r) s_q[r][j] = acc[r];
        }
        __syncthreads();
        // phase D2: posterior sample + carry update + output writes
        if (tid < R * NS) {
            const int r = tid / NS, i = tid % NS;
            const size_t bt = (size_t)(b0 + r) * NT + t;
            const float qm = s_q[r][i];
            const float qs = sp_f(s_q[r][NS + i]) + 0.1f;
            const float qst = noise_post[bt * NS + i] * qs + qm;
            out[bt * OC + i]       = qm;
            out[bt * OC + 30 + i]  = qs;
            out[bt * OC + 60 + i]  = qst;
            s_in[r][i] = qst;  // next stoch
        }
        if (tid < ND) {
            #pragma unroll
            for (int r = 0; r < R; ++r) {
                const float v = s_dnew[r][tid];
                s_deter[r][tid] = v;
                const size_t bt = (size_t)(b0 + r) * NT + t;
                out[bt * OC + 90 + tid]  = v;   // post deter
                out[bt * OC + 380 + tid] = v;   // prior deter
            }
        }
        __syncthreads();
    }
}

// ---------------------------------------------------------------------------
// Prior head, batched over all (b,t): 2048 blocks x 32 rows.
// ---------------------------------------------------------------------------
__global__ __launch_bounds__(256) void prior_kernel(
    const float* __restrict__ noise_prior,
    const float* __restrict__ Wp1, const float* __restrict__ bp1,
    const float* __restrict__ Wp2, const float* __restrict__ bp2,
    float* __restrict__ out)
{
    __shared__ float s_d[PG][200];
    __shared__ float s_hp[PG][200];
    __shared__ float s_p[PG][60];
    const int tid = threadIdx.x;
    const size_t bt0 = (size_t)blockIdx.x * PG;

    for (int idx = tid; idx < PG * 50; idx += 256) {
        const int i = idx / 50, kq = (idx % 50) * 4;
        *reinterpret_cast<float4*>(&s_d[i][kq]) =
            *reinterpret_cast<const float4*>(&out[(bt0 + i) * OC + 380 + kq]);
    }
    __syncthreads();
    if (tid < 200) {   // hp = elu(deter @ Wp1^T + bp1)
        const int j = tid;
        float acc[PG];
        #pragma unroll
        for (int i = 0; i < PG; ++i) acc[i] = bp1[j];
        const float* w = &Wp1[(size_t)j * 200];
        for (int k0 = 0; k0 < 200; k0 += 8) {
            const float4 w0 = *reinterpret_cast<const float4*>(&w[k0]);
            const float4 w1 = *reinterpret_cast<const float4*>(&w[k0 + 4]);
            #pragma unroll
            for (int i = 0; i < PG; ++i) {
                const float4 s0 = *reinterpret_cast<const float4*>(&s_d[i][k0]);
                const float4 s1 = *reinterpret_cast<const float4*>(&s_d[i][k0 + 4]);
                acc[i] += w0.x * s0.x + w0.y * s0.y + w0.z * s0.z + w0.w * s0.w
                        + w1.x * s1.x + w1.y * s1.y + w1.z * s1.z + w1.w * s1.w;
            }
        }
        #pragma unroll
        for (int i = 0; i < PG; ++i) s_hp[i][j] = elu_f(acc[i]);
    }
    __syncthreads();
    if (tid < 240) {   // [pm|ps]_raw = hp @ Wp2^T + bp2 ; 4 groups of 8 rows
        const int j = tid % 60, ig = (tid / 60) * 8;
        float acc[8];
        #pragma unroll
        for (int i = 0; i < 8; ++i) acc[i] = bp2[j];
        const float* w = &Wp2[(size_t)j * 200];
        for (int k0 = 0; k0 < 200; k0 += 8) {
            const float4 w0 = *reinterpret_cast<const float4*>(&w[k0]);
            const float4 w1 = *reinterpret_cast<const float4*>(&w[k0 + 4]);
            #pragma unroll
            for (int i = 0; i < 8; ++i) {
                const float4 s0 = *reinterpret_cast<const float4*>(&s_hp[ig + i][k0]);
                const float4 s1 = *reinterpret_cast<const float4*>(&s_hp[ig + i][k0 + 4]);
                acc[i] += w0.x * s0.x + w0.y * s0.y + w0.z * s0.z + w0.w * s0.w
                        + w1.x * s1.x + w1.y * s1.y + w1.z * s1.z + w1.w * s1.w;
            }
        }
        #pragma unroll
        for (int i = 0; i < 8; ++i) s_p[ig + i][j] = acc[i];
    }
    __syncthreads();
    for (int idx = tid; idx < PG * NS; idx += 256) {
        const int i = idx / NS, ss = idx % NS;
        const float pm = s_p[i][ss];
        const float ps = sp_f(s_p[i][NS + ss]) + 0.1f;
        const float pst = noise_prior[(bt0 + i) * NS + ss] * ps + pm;
        const size_t base = (bt0 + i) * OC;
        out[base + 290 + ss] = pm;
        out[base + 320 + ss] = ps;
        out[base + 350 + ss] = pst;
    }
}

extern "C" void kernel_launch(void* const* d_in, const int* in_sizes, int n_in,
                              void* d_out, int out_size, void* d_ws, size_t ws_size,
                              hipStream_t stream)
{
    (void)in_sizes; (void)n_in; (void)out_size; (void)d_ws; (void)ws_size;
    const float* embed       = (const float*)d_in[0];
    const float* action      = (const float*)d_in[1];
    const float* noise_prior = (const float*)d_in[2];
    const float* noise_post  = (const float*)d_in[3];
    const float* Wi   = (const float*)d_in[4];
    const float* bi   = (const float*)d_in[5];
    const float* W_ih = (const float*)d_in[6];
    const float* W_hh = (const float*)d_in[7];
    const float* b_ih = (const float*)d_in[8];
    const float* b_hh = (const float*)d_in[9];
    const float* Wp1  = (const float*)d_in[10];
    const float* bp1  = (const float*)d_in[11];
    const float* Wp2  = (const float*)d_in[12];
    const float* bp2  = (const float*)d_in[13];
    const float* Wq1  = (const float*)d_in[14];
    const float* bq1  = (const float*)d_in[15];
    const float* Wq2  = (const float*)d_in[16];
    const float* bq2  = (const float*)d_in[17];
    float* out = (float*)d_out;

    hipLaunchKernelGGL(epre_kernel, dim3(NB * NT / 64), dim3(256), 0, stream,
                       embed, Wq1, bq1, out);
    hipLaunchKernelGGL(scan_kernel, dim3(NB / R), dim3(256), 0, stream,
                       action, noise_post, Wi, bi, W_ih, W_hh, b_ih, b_hh,
                       Wq1, Wq2, bq2, out);
    hipLaunchKernelGGL(prior_kernel, dim3(NB * NT / PG), dim3(256), 0, stream,
                       noise_prior, Wp1, bp1, Wp2, bp2, out);
}

// Round 2
// 2594.317 us; speedup vs baseline: 1.4707x; 1.4707x over previous
//
#include <hip/hip_runtime.h>
#include <math.h>

typedef unsigned short u16;
typedef unsigned int   u32;
typedef __attribute__((ext_vector_type(8))) short short8;
typedef __attribute__((ext_vector_type(4))) float f32x4;

#define NBATCH 1024
#define NT 64
#define OC 580
#define RB 16            // batch rows per scan block
#define SCAN_BLOCKS (NBATCH / RB)
#define SX 232           // bf16 LDS row stride (116 dwords -> uniform b128 banking)
#define SF 212           // f32 LDS row stride (212%32=20 -> 2-way max on tile stores)
// packed bf16 weight offsets in d_ws (u16 units)
#define P_WI    0        // 13 ntiles x 2 ksteps x 1024
#define P_WIH   26624    // 3 gates x 13 ntiles x 7 ksteps x 1024
#define P_WHH   306176
#define P_WQ1   585728   // 13 x 7 x 1024
#define P_WQ2   678912   // 4 x 7 x 1024
#define P_TOTAL 707584

__device__ __forceinline__ float elu_f(float x) { return x > 0.f ? x : __expf(x) - 1.f; }
__device__ __forceinline__ float sig_f(float x) { return 1.f / (1.f + __expf(-x)); }
__device__ __forceinline__ float sp_f(float x)  { return x > 20.f ? x : log1pf(__expf(x)); }

__device__ __forceinline__ u16 f2b(float f) {   // f32 -> bf16 RNE
    union { float f; u32 u; } v; v.f = f;
    u32 r = (v.u + 0x7fffu + ((v.u >> 16) & 1u)) >> 16;
    return (u16)r;
}

#define MFMA(a, b, c) __builtin_amdgcn_mfma_f32_16x16x32_bf16((a), (b), (c), 0, 0, 0)

// ---------------------------------------------------------------------------
// Pack scan weights to bf16 in MFMA B-fragment order:
// packed[tile][lane][e] = W[n0 + (lane&15)][k0 + (lane>>4)*8 + e]  (0-padded)
// ---------------------------------------------------------------------------
__global__ __launch_bounds__(256) void prep_pack(
    const float* __restrict__ Wi, const float* __restrict__ W_ih,
    const float* __restrict__ W_hh, const float* __restrict__ Wq1,
    const float* __restrict__ Wq2, u16* __restrict__ wp)
{
    for (size_t r = (size_t)blockIdx.x * 256 + threadIdx.x; r < P_TOTAL;
         r += (size_t)gridDim.x * 256) {
        float val = 0.f;
        if (r < P_WIH) {                           // Wi: [200 x 36] pad [208 x 64]
            int tile = r / 1024, lane = (r % 1024) / 8, el = r % 8;
            int tt = tile / 2, ks = tile % 2;
            int j = tt * 16 + (lane & 15), k = ks * 32 + (lane >> 4) * 8 + el;
            if (j < 200 && k < 36) val = Wi[j * 36 + k];
        } else if (r < P_WHH) {                    // W_ih: 3 x [200 x 200] pad [208 x 224]
            size_t q = r - P_WIH;
            int tile = q / 1024, lane = (q % 1024) / 8, el = q % 8;
            int g = tile / 91, rem = tile % 91, tt = rem / 7, ks = rem % 7;
            int j = tt * 16 + (lane & 15), k = ks * 32 + (lane >> 4) * 8 + el;
            if (j < 200 && k < 200) val = W_ih[(size_t)(g * 200 + j) * 200 + k];
        } else if (r < P_WQ1) {                    // W_hh
            size_t q = r - P_WHH;
            int tile = q / 1024, lane = (q % 1024) / 8, el = q % 8;
            int g = tile / 91, rem = tile % 91, tt = rem / 7, ks = rem % 7;
            int j = tt * 16 + (lane & 15), k = ks * 32 + (lane >> 4) * 8 + el;
            if (j < 200 && k < 200) val = W_hh[(size_t)(g * 200 + j) * 200 + k];
        } else if (r < P_WQ2) {                    // Wq1[:, :200]: [200 x 200]
            size_t q = r - P_WQ1;
            int tile = q / 1024, lane = (q % 1024) / 8, el = q % 8;
            int tt = tile / 7, ks = tile % 7;
            int j = tt * 16 + (lane & 15), k = ks * 32 + (lane >> 4) * 8 + el;
            if (j < 200 && k < 200) val = Wq1[(size_t)j * 1224 + k];
        } else {                                   // Wq2: [60 x 200] pad [64 x 224]
            size_t q = r - P_WQ2;
            int tile = q / 1024, lane = (q % 1024) / 8, el = q % 8;
            int tt = tile / 7, ks = tile % 7;
            int j = tt * 16 + (lane & 15), k = ks * 32 + (lane >> 4) * 8 + el;
            if (j < 60 && k < 200) val = Wq2[(size_t)j * 200 + k];
        }
        wp[r] = f2b(val);
    }
}

// ---------------------------------------------------------------------------
// Epre[bt][j] = embed[bt][:] . Wq1[j][200:1224] + bq1[j] -> out[bt*580+290+j]
// (unchanged from round 1)
// ---------------------------------------------------------------------------
__global__ __launch_bounds__(256) void epre_kernel(
    const float* __restrict__ embed, const float* __restrict__ Wq1,
    const float* __restrict__ bq1, float* __restrict__ out)
{
    __shared__ float s_a[16][68];
    __shared__ float s_w[200][17];
    const int tid = threadIdx.x;
    const int tx = tid & 15, ty = tid >> 4;
    const int bt0 = blockIdx.x * 64;
    float acc[4][13];
    #pragma unroll
    for (int r = 0; r < 4; ++r)
        #pragma unroll
        for (int c = 0; c < 13; ++c) acc[r][c] = 0.f;

    for (int k0 = 0; k0 < 1024; k0 += 16) {
        {
            const int i = tid >> 2, kq = (tid & 3) * 4;
            const float4 v = *reinterpret_cast<const float4*>(
                &embed[(size_t)(bt0 + i) * 1024 + k0 + kq]);
            s_a[kq + 0][i] = v.x; s_a[kq + 1][i] = v.y;
            s_a[kq + 2][i] = v.z; s_a[kq + 3][i] = v.w;
        }
        for (int idx = tid; idx < 800; idx += 256) {
            const int j = idx >> 2, kq = (idx & 3) * 4;
            const float4 v = *reinterpret_cast<const float4*>(
                &Wq1[(size_t)j * 1224 + 200 + k0 + kq]);
            s_w[j][kq + 0] = v.x; s_w[j][kq + 1] = v.y;
            s_w[j][kq + 2] = v.z; s_w[j][kq + 3] = v.w;
        }
        __syncthreads();
        #pragma unroll
        for (int kk = 0; kk < 16; ++kk) {
            const float4 a4 = *reinterpret_cast<const float4*>(&s_a[kk][ty * 4]);
            #pragma unroll
            for (int c = 0; c < 12; ++c) {
                const float w = s_w[tx + 16 * c][kk];
                acc[0][c] += a4.x * w; acc[1][c] += a4.y * w;
                acc[2][c] += a4.z * w; acc[3][c] += a4.w * w;
            }
            if (tx < 8) {
                const float w = s_w[tx + 192][kk];
                acc[0][12] += a4.x * w; acc[1][12] += a4.y * w;
                acc[2][12] += a4.z * w; acc[3][12] += a4.w * w;
            }
        }
        __syncthreads();
    }
    #pragma unroll
    for (int r = 0; r < 4; ++r) {
        const int i = ty * 4 + r;
        #pragma unroll
        for (int c = 0; c < 12; ++c) {
            const int j = tx + 16 * c;
            out[(size_t)(bt0 + i) * OC + 290 + j] = acc[r][c] + bq1[j];
        }
        if (tx < 8)
            out[(size_t)(bt0 + i) * OC + 290 + tx + 192] = acc[r][12] + bq1[tx + 192];
    }
}

// ---------------------------------------------------------------------------
// MFMA scan: 64 blocks x 16 batch rows, 512 threads (8 waves), t-loop inside.
// ---------------------------------------------------------------------------
__global__ __launch_bounds__(512) void scan_mfma(
    const float* __restrict__ action, const float* __restrict__ noise_post,
    const float* __restrict__ b_ih, const float* __restrict__ b_hh,
    const float* __restrict__ bi, const float* __restrict__ bq2,
    const u16* __restrict__ wp, float* __restrict__ out)
{
    __shared__ u16   s_in0[RB][72];           // [stoch30 | act6 | 0pad], K=64 used
    __shared__ u16   s_x[RB][SX];             // x bf16
    __shared__ u16   s_db[RB][SX];            // deter bf16 (MFMA shadow)
    __shared__ u16   s_hq[RB][SX];            // hq bf16
    __shared__ float s_df[RB][200];           // deter fp32 carry
    __shared__ float s_ep[RB][SF];            // Epre staged fp32
    __shared__ float s_r[RB][SF], s_z[RB][SF], s_inn[RB][SF], s_hnn[RB][SF];
    __shared__ float s_q[RB][64];
    __shared__ float s_bih[3][208], s_bhh[3][208], s_bi[208], s_bq2[64];

    const int tid  = threadIdx.x;
    const int wv   = tid >> 6, ln = tid & 63;
    const int arow = ln & 15, kgrp = ln >> 4;
    const int b0   = blockIdx.x * RB;

    // init: zero bf16 activations (incl. K-pads) + s_ep + s_df, stage biases
    { u32* z = (u32*)s_in0; for (int i = tid; i < RB*72/2;  i += 512) z[i] = 0; }
    { u32* z = (u32*)s_x;   for (int i = tid; i < RB*SX/2;  i += 512) z[i] = 0; }
    { u32* z = (u32*)s_db;  for (int i = tid; i < RB*SX/2;  i += 512) z[i] = 0; }
    { u32* z = (u32*)s_hq;  for (int i = tid; i < RB*SX/2;  i += 512) z[i] = 0; }
    { float* z = (float*)s_ep; for (int i = tid; i < RB*SF; i += 512) z[i] = 0.f; }
    { float* z = (float*)s_df; for (int i = tid; i < RB*200; i += 512) z[i] = 0.f; }
    for (int i = tid; i < 3 * 208; i += 512) {
        int g = i / 208, j = i % 208;
        s_bih[g][j] = j < 200 ? b_ih[g * 200 + j] : 0.f;
        s_bhh[g][j] = j < 200 ? b_hh[g * 200 + j] : 0.f;
    }
    for (int i = tid; i < 208; i += 512) s_bi[i] = i < 200 ? bi[i] : 0.f;
    if (tid < 64) s_bq2[tid] = tid < 60 ? bq2[tid] : 0.f;
    __syncthreads();

    for (int t = 0; t < NT; ++t) {
        // ---- stage Epre (16x200, written by epre_kernel) + action(t) ----
        for (int idx = tid; idx < RB * 200; idx += 512) {
            int i = idx / 200, j = idx % 200;
            s_ep[i][j] = out[((size_t)(b0 + i) * NT + t) * OC + 290 + j];
        }
        if (tid < RB * 6) {
            int i = tid / 6, c = tid % 6;
            s_in0[i][30 + c] = f2b(action[((size_t)(b0 + i) * NT + t) * 6 + c]);
        }
        __syncthreads();

        // ---- phase A: x = elu([stoch|act] @ Wi^T + bi), 13 n-tiles ----
        for (int tt = wv; tt < 13; tt += 8) {
            float bv = s_bi[tt * 16 + arow];
            f32x4 acc = {bv, bv, bv, bv};
            #pragma unroll
            for (int ks = 0; ks < 2; ++ks) {
                short8 af = *(const short8*)&s_in0[arow][ks * 32 + kgrp * 8];
                short8 wf = *(const short8*)&wp[P_WI + (size_t)(tt * 2 + ks) * 1024 + ln * 8];
                acc = MFMA(af, wf, acc);
            }
            #pragma unroll
            for (int e = 0; e < 4; ++e)
                s_x[kgrp * 4 + e][tt * 16 + arow] = f2b(elu_f(acc[e]));
        }
        __syncthreads();

        // ---- phase B: gi = x@W_ih^T, gh = deter@W_hh^T ; 39 (gate,tile) pairs ----
        {
            f32x4 gi[5], gh[5];
            #pragma unroll
            for (int q = 0; q < 5; ++q) {
                int p = wv + 8 * q; int pe = p < 39 ? p : 0;
                int g = pe / 13, tt = pe % 13;
                float b1 = s_bih[g][tt * 16 + arow];
                float b2 = s_bhh[g][tt * 16 + arow];
                gi[q] = (f32x4){b1, b1, b1, b1};
                gh[q] = (f32x4){b2, b2, b2, b2};
            }
            for (int ks = 0; ks < 7; ++ks) {
                short8 ax = *(const short8*)&s_x[arow][ks * 32 + kgrp * 8];
                short8 ad = *(const short8*)&s_db[arow][ks * 32 + kgrp * 8];
                #pragma unroll
                for (int q = 0; q < 5; ++q) {
                    int p = wv + 8 * q; int pe = p < 39 ? p : 0;
                    short8 w1 = *(const short8*)&wp[P_WIH + ((size_t)pe * 7 + ks) * 1024 + ln * 8];
                    short8 w2 = *(const short8*)&wp[P_WHH + ((size_t)pe * 7 + ks) * 1024 + ln * 8];
                    gi[q] = MFMA(ax, w1, gi[q]);
                    gh[q] = MFMA(ad, w2, gh[q]);
                }
            }
            #pragma unroll
            for (int q = 0; q < 5; ++q) {
                int p = wv + 8 * q;
                if (p < 39) {
                    int g = p / 13, tt = p % 13, j = tt * 16 + arow;
                    #pragma unroll
                    for (int e = 0; e < 4; ++e) {
                        int i = kgrp * 4 + e;
                        if (g == 0)      s_r[i][j] = sig_f(gi[q][e] + gh[q][e]);
                        else if (g == 1) s_z[i][j] = sig_f(gi[q][e] + gh[q][e]);
                        else { s_inn[i][j] = gi[q][e]; s_hnn[i][j] = gh[q][e]; }
                    }
                }
            }
        }
        __syncthreads();

        // ---- GRU combine: deter_new = (1-z)*tanh(inn + r*hnn) + z*deter ----
        for (int idx = tid; idx < RB * 200; idx += 512) {
            int i = idx / 200, j = idx % 200;
            float rr = s_r[i][j], zz = s_z[i][j];
            float nn = tanhf(s_inn[i][j] + rr * s_hnn[i][j]);
            float d = (1.f - zz) * nn + zz * s_df[i][j];
            s_df[i][j] = d;
            s_db[i][j] = f2b(d);
            size_t o = ((size_t)(b0 + i) * NT + t) * OC;
            out[o + 90 + j]  = d;   // post deter
            out[o + 380 + j] = d;   // prior deter
        }
        __syncthreads();

        // ---- phase C: hq = elu(deter_new @ Wq1a^T + Epre) ----
        for (int tt = wv; tt < 13; tt += 8) {
            int j = tt * 16 + arow;
            f32x4 acc;
            #pragma unroll
            for (int e = 0; e < 4; ++e) acc[e] = s_ep[kgrp * 4 + e][j];
            for (int ks = 0; ks < 7; ++ks) {
                short8 ad = *(const short8*)&s_db[arow][ks * 32 + kgrp * 8];
                short8 wf = *(const short8*)&wp[P_WQ1 + ((size_t)tt * 7 + ks) * 1024 + ln * 8];
                acc = MFMA(ad, wf, acc);
            }
            #pragma unroll
            for (int e = 0; e < 4; ++e)
                s_hq[kgrp * 4 + e][j] = f2b(elu_f(acc[e]));
        }
        __syncthreads();

        // ---- phase D1: q = hq @ Wq2^T + bq2 (4 n-tiles on waves 0-3) ----
        if (wv < 4) {
            int tt = wv, j = tt * 16 + arow;
            float bv = s_bq2[j];
            f32x4 acc = {bv, bv, bv, bv};
            for (int ks = 0; ks < 7; ++ks) {
                short8 ah = *(const short8*)&s_hq[arow][ks * 32 + kgrp * 8];
                short8 wf = *(const short8*)&wp[P_WQ2 + ((size_t)tt * 7 + ks) * 1024 + ln * 8];
                acc = MFMA(ah, wf, acc);
            }
            #pragma unroll
            for (int e = 0; e < 4; ++e) s_q[kgrp * 4 + e][j] = acc[e];
        }
        __syncthreads();

        // ---- phase D2: posterior sample + outputs + next stoch ----
        if (tid < RB * 30) {
            int i = tid / 30, s = tid % 30;
            float qm = s_q[i][s];
            float qs = sp_f(s_q[i][30 + s]) + 0.1f;
            size_t bt = (size_t)(b0 + i) * NT + t;
            float qst = noise_post[bt * 30 + s] * qs + qm;
            size_t o = bt * OC;
            out[o + s]      = qm;
            out[o + 30 + s] = qs;
            out[o + 60 + s] = qst;
            s_in0[i][s] = f2b(qst);
        }
        // no barrier needed: next stage writes disjoint LDS; barrier follows it
    }
}

// ---------------------------------------------------------------------------
// Prior head, batched over all (b,t) (unchanged from round 1)
// ---------------------------------------------------------------------------
#define PG 32
__global__ __launch_bounds__(256) void prior_kernel(
    const float* __restrict__ noise_prior,
    const float* __restrict__ Wp1, const float* __restrict__ bp1,
    const float* __restrict__ Wp2, const float* __restrict__ bp2,
    float* __restrict__ out)
{
    __shared__ float s_d[PG][200];
    __shared__ float s_hp[PG][200];
    __shared__ float s_p[PG][60];
    const int tid = threadIdx.x;
    const size_t bt0 = (size_t)blockIdx.x * PG;

    for (int idx = tid; idx < PG * 50; idx += 256) {
        const int i = idx / 50, kq = (idx % 50) * 4;
        *reinterpret_cast<float4*>(&s_d[i][kq]) =
            *reinterpret_cast<const float4*>(&out[(bt0 + i) * OC + 380 + kq]);
    }
    __syncthreads();
    if (tid < 200) {
        const int j = tid;
        float acc[PG];
        #pragma unroll
        for (int i = 0; i < PG; ++i) acc[i] = bp1[j];
        const float* w = &Wp1[(size_t)j * 200];
        for (int k0 = 0; k0 < 200; k0 += 8) {
            const float4 w0 = *reinterpret_cast<const float4*>(&w[k0]);
            const float4 w1 = *reinterpret_cast<const float4*>(&w[k0 + 4]);
            #pragma unroll
            for (int i = 0; i < PG; ++i) {
                const float4 s0 = *reinterpret_cast<const float4*>(&s_d[i][k0]);
                const float4 s1 = *reinterpret_cast<const float4*>(&s_d[i][k0 + 4]);
                acc[i] += w0.x * s0.x + w0.y * s0.y + w0.z * s0.z + w0.w * s0.w
                        + w1.x * s1.x + w1.y * s1.y + w1.z * s1.z + w1.w * s1.w;
            }
        }
        #pragma unroll
        for (int i = 0; i < PG; ++i) s_hp[i][j] = elu_f(acc[i]);
    }
    __syncthreads();
    if (tid < 240) {
        const int j = tid % 60, ig = (tid / 60) * 8;
        float acc[8];
        #pragma unroll
        for (int i = 0; i < 8; ++i) acc[i] = bp2[j];
        const float* w = &Wp2[(size_t)j * 200];
        for (int k0 = 0; k0 < 200; k0 += 8) {
            const float4 w0 = *reinterpret_cast<const float4*>(&w[k0]);
            const float4 w1 = *reinterpret_cast<const float4*>(&w[k0 + 4]);
            #pragma unroll
            for (int i = 0; i < 8; ++i) {
                const float4 s0 = *reinterpret_cast<const float4*>(&s_hp[ig + i][k0]);
                const float4 s1 = *reinterpret_cast<const float4*>(&s_hp[ig + i][k0 + 4]);
                acc[i] += w0.x * s0.x + w0.y * s0.y + w0.z * s0.z + w0.w * s0.w
                        + w1.x * s1.x + w1.y * s1.y + w1.z * s1.z + w1.w * s1.w;
            }
        }
        #pragma unroll
        for (int i = 0; i < 8; ++i) s_p[ig + i][j] = acc[i];
    }
    __syncthreads();
    for (int idx = tid; idx < PG * 30; idx += 256) {
        const int i = idx / 30, ss = idx % 30;
        const float pm = s_p[i][ss];
        const float ps = sp_f(s_p[i][30 + ss]) + 0.1f;
        const float pst = noise_prior[(bt0 + i) * 30 + ss] * ps + pm;
        const size_t base = (bt0 + i) * OC;
        out[base + 290 + ss] = pm;
        out[base + 320 + ss] = ps;
        out[base + 350 + ss] = pst;
    }
}

extern "C" void kernel_launch(void* const* d_in, const int* in_sizes, int n_in,
                              void* d_out, int out_size, void* d_ws, size_t ws_size,
                              hipStream_t stream)
{
    (void)in_sizes; (void)n_in; (void)out_size; (void)ws_size;
    const float* embed       = (const float*)d_in[0];
    const float* action      = (const float*)d_in[1];
    const float* noise_prior = (const float*)d_in[2];
    const float* noise_post  = (const float*)d_in[3];
    const float* Wi   = (const float*)d_in[4];
    const float* bi   = (const float*)d_in[5];
    const float* W_ih = (const float*)d_in[6];
    const float* W_hh = (const float*)d_in[7];
    const float* b_ih = (const float*)d_in[8];
    const float* b_hh = (const float*)d_in[9];
    const float* Wp1  = (const float*)d_in[10];
    const float* bp1  = (const float*)d_in[11];
    const float* Wp2  = (const float*)d_in[12];
    const float* bp2  = (const float*)d_in[13];
    const float* Wq1  = (const float*)d_in[14];
    const float* bq1  = (const float*)d_in[15];
    const float* Wq2  = (const float*)d_in[16];
    const float* bq2  = (const float*)d_in[17];
    float* out = (float*)d_out;
    u16* wp = (u16*)d_ws;

    hipLaunchKernelGGL(prep_pack, dim3((P_TOTAL + 255) / 256), dim3(256), 0, stream,
                       Wi, W_ih, W_hh, Wq1, Wq2, wp);
    hipLaunchKernelGGL(epre_kernel, dim3(NBATCH * NT / 64), dim3(256), 0, stream,
                       embed, Wq1, bq1, out);
    hipLaunchKernelGGL(scan_mfma, dim3(SCAN_BLOCKS), dim3(512), 0, stream,
                       action, noise_post, b_ih, b_hh, bi, bq2, wp, out);
    hipLaunchKernelGGL(prior_kernel, dim3(NBATCH * NT / PG), dim3(256), 0, stream,
                       noise_prior, Wp1, bp1, Wp2, bp2, out);
}

// Round 3
// 1769.919 us; speedup vs baseline: 2.1557x; 1.4658x over previous
//
#include <hip/hip_runtime.h>
#include <math.h>

typedef unsigned short u16;
typedef unsigned int   u32;
typedef __attribute__((ext_vector_type(8))) short short8;
typedef __attribute__((ext_vector_type(4))) float f32x4;

#define NT 64
#define OC 580
#define RB 16
#define SX 232           // bf16 LDS row stride (116 dwords -> <=2-way banks, 16B aligned)

// packed bf16 weight offsets in d_ws (u16 units)
#define P_WI    0                      // [tt13][ks2][1024]
#define P_WIH   26624                  // [(g*13+tt)][ks7][1024]
#define P_WHH   306176
#define P_WQ1   585728                 // [tt13][ks7][1024]
#define P_WQ2   678912                 // [tt4][ks7][1024]
#define P_EB    707584                 // [ks32][tt13][1024]   (epre B: Wq1[:,200:1224])
#define P_WP1   1133568                // [ks7][tt13][1024]
#define P_WP2   1226752                // [ks7][tt4][1024]
#define P_TOTAL 1255424                // 2.51 MB

__device__ __forceinline__ float elu_f(float x) { return x > 0.f ? x : __expf(x) - 1.f; }
__device__ __forceinline__ float sig_f(float x) { return 1.f / (1.f + __expf(-x)); }
__device__ __forceinline__ float sp_f(float x)  { return x > 20.f ? x : log1pf(__expf(x)); }

__device__ __forceinline__ u16 f2b(float f) {   // f32 -> bf16 RNE
    union { float f; u32 u; } v; v.f = f;
    u32 r = (v.u + 0x7fffu + ((v.u >> 16) & 1u)) >> 16;
    return (u16)r;
}

__device__ __forceinline__ short8 pack8(float4 v0, float4 v1) {
    short8 r;
    r[0] = (short)f2b(v0.x); r[1] = (short)f2b(v0.y);
    r[2] = (short)f2b(v0.z); r[3] = (short)f2b(v0.w);
    r[4] = (short)f2b(v1.x); r[5] = (short)f2b(v1.y);
    r[6] = (short)f2b(v1.z); r[7] = (short)f2b(v1.w);
    return r;
}

#define MFMA(a, b, c) __builtin_amdgcn_mfma_f32_16x16x32_bf16((a), (b), (c), 0, 0, 0)

// ---------------------------------------------------------------------------
// Pack all weights to bf16 MFMA B-fragment order:
// frag[lane][e] = W[n0 + (lane&15)][k0 + (lane>>4)*8 + e]  (0-padded)
// ---------------------------------------------------------------------------
__global__ __launch_bounds__(256) void prep_pack(
    const float* __restrict__ Wi, const float* __restrict__ W_ih,
    const float* __restrict__ W_hh, const float* __restrict__ Wq1,
    const float* __restrict__ Wq2, const float* __restrict__ Wp1,
    const float* __restrict__ Wp2, u16* __restrict__ wp)
{
    for (size_t r = (size_t)blockIdx.x * 256 + threadIdx.x; r < P_TOTAL;
         r += (size_t)gridDim.x * 256) {
        float val = 0.f;
        if (r < P_WIH) {                           // Wi: [200 x 36] pad [208 x 64]
            int tile = r / 1024, lane = (r % 1024) / 8, el = r % 8;
            int tt = tile / 2, ks = tile % 2;
            int j = tt * 16 + (lane & 15), k = ks * 32 + (lane >> 4) * 8 + el;
            if (j < 200 && k < 36) val = Wi[j * 36 + k];
        } else if (r < P_WHH) {                    // W_ih
            size_t q = r - P_WIH;
            int tile = q / 1024, lane = (q % 1024) / 8, el = q % 8;
            int g = tile / 91, rem = tile % 91, tt = rem / 7, ks = rem % 7;
            int j = tt * 16 + (lane & 15), k = ks * 32 + (lane >> 4) * 8 + el;
            if (j < 200 && k < 200) val = W_ih[(size_t)(g * 200 + j) * 200 + k];
        } else if (r < P_WQ1) {                    // W_hh
            size_t q = r - P_WHH;
            int tile = q / 1024, lane = (q % 1024) / 8, el = q % 8;
            int g = tile / 91, rem = tile % 91, tt = rem / 7, ks = rem % 7;
            int j = tt * 16 + (lane & 15), k = ks * 32 + (lane >> 4) * 8 + el;
            if (j < 200 && k < 200) val = W_hh[(size_t)(g * 200 + j) * 200 + k];
        } else if (r < P_WQ2) {                    // Wq1[:, :200]
            size_t q = r - P_WQ1;
            int tile = q / 1024, lane = (q % 1024) / 8, el = q % 8;
            int tt = tile / 7, ks = tile % 7;
            int j = tt * 16 + (lane & 15), k = ks * 32 + (lane >> 4) * 8 + el;
            if (j < 200 && k < 200) val = Wq1[(size_t)j * 1224 + k];
        } else if (r < P_EB) {                     // Wq2: [60 x 200] pad [64 x 224]
            size_t q = r - P_WQ2;
            int tile = q / 1024, lane = (q % 1024) / 8, el = q % 8;
            int tt = tile / 7, ks = tile % 7;
            int j = tt * 16 + (lane & 15), k = ks * 32 + (lane >> 4) * 8 + el;
            if (j < 60 && k < 200) val = Wq2[(size_t)j * 200 + k];
        } else if (r < P_WP1) {                    // epre B: Wq1[:,200:1224], [ks32][tt13]
            size_t q = r - P_EB;
            int tile = q / 1024, lane = (q % 1024) / 8, el = q % 8;
            int ks = tile / 13, tt = tile % 13;
            int j = tt * 16 + (lane & 15), k = ks * 32 + (lane >> 4) * 8 + el;
            if (j < 200) val = Wq1[(size_t)j * 1224 + 200 + k];
        } else if (r < P_WP2) {                    // Wp1: [200 x 200], [ks7][tt13]
            size_t q = r - P_WP1;
            int tile = q / 1024, lane = (q % 1024) / 8, el = q % 8;
            int ks = tile / 13, tt = tile % 13;
            int j = tt * 16 + (lane & 15), k = ks * 32 + (lane >> 4) * 8 + el;
            if (j < 200 && k < 200) val = Wp1[(size_t)j * 200 + k];
        } else {                                   // Wp2: [60 x 200], [ks7][tt4]
            size_t q = r - P_WP2;
            int tile = q / 1024, lane = (q % 1024) / 8, el = q % 8;
            int ks = tile / 4, tt = tile % 4;
            int j = tt * 16 + (lane & 15), k = ks * 32 + (lane >> 4) * 8 + el;
            if (j < 60 && k < 200) val = Wp2[(size_t)j * 200 + k];
        }
        wp[r] = f2b(val);
    }
}

// ---------------------------------------------------------------------------
// Epre (MFMA): out[bt*580+290+j] = embed[bt] . Wq1[j][200:] + bq1[j]
// 256 blocks x 512 thr (8 waves x 32 rows), no LDS, A converted in-register.
// ---------------------------------------------------------------------------
__global__ __launch_bounds__(512) void epre_mfma(
    const float* __restrict__ embed, const u16* __restrict__ wp,
    const float* __restrict__ bq1, float* __restrict__ out)
{
    const int tid = threadIdx.x;
    const int wv = tid >> 6, ln = tid & 63;
    const int arow = ln & 15, kgrp = ln >> 4;
    const int m0 = blockIdx.x * 256 + wv * 32;

    f32x4 acc[2][13];
    #pragma unroll
    for (int tt = 0; tt < 13; ++tt) {
        const int j = tt * 16 + arow;
        const float bv = (j < 200) ? bq1[j] : 0.f;
        acc[0][tt] = (f32x4){bv, bv, bv, bv};
        acc[1][tt] = acc[0][tt];
    }
    const float* e0 = &embed[(size_t)(m0 + arow) * 1024 + kgrp * 8];
    const float* e1 = e0 + (size_t)16 * 1024;

    for (int ks = 0; ks < 32; ++ks) {
        short8 a0, a1;
        {
            float4 v0 = *(const float4*)(e0 + ks * 32);
            float4 v1 = *(const float4*)(e0 + ks * 32 + 4);
            a0 = pack8(v0, v1);
            float4 w0 = *(const float4*)(e1 + ks * 32);
            float4 w1 = *(const float4*)(e1 + ks * 32 + 4);
            a1 = pack8(w0, w1);
        }
        const u16* bp = &wp[P_EB + (size_t)ks * 13 * 1024 + (size_t)ln * 8];
        #pragma unroll
        for (int tt = 0; tt < 13; ++tt) {
            short8 b = *(const short8*)(bp + (size_t)tt * 1024);
            acc[0][tt] = MFMA(a0, b, acc[0][tt]);
            acc[1][tt] = MFMA(a1, b, acc[1][tt]);
        }
    }
    #pragma unroll
    for (int f = 0; f < 2; ++f) {
        const size_t rbase = (size_t)(m0 + f * 16 + kgrp * 4);
        #pragma unroll
        for (int tt = 0; tt < 13; ++tt) {
            const int j = tt * 16 + arow;
            if (j < 200) {
                #pragma unroll
                for (int e = 0; e < 4; ++e)
                    out[(rbase + e) * OC + 290 + j] = acc[f][tt][e];
            }
        }
    }
}

// ---------------------------------------------------------------------------
// MFMA scan: 64 blocks x 16 rows, 512 thr (8 waves). In-register GRU combine,
// double-buffered bf16 deter, fp32 carry in transposed LDS, 5 barriers/step.
// ---------------------------------------------------------------------------
__global__ __launch_bounds__(512) void scan_mfma(
    const float* __restrict__ action, const float* __restrict__ noise_post,
    const float* __restrict__ b_ih, const float* __restrict__ b_hh,
    const float* __restrict__ bi, const float* __restrict__ bq2,
    const u16* __restrict__ wp, float* __restrict__ out)
{
    __shared__ __align__(16) u16   s_in0[RB][72];
    __shared__ __align__(16) u16   s_x[RB][SX];
    __shared__ __align__(16) u16   s_db[2][RB][SX];
    __shared__ __align__(16) u16   s_hq[RB][SX];
    __shared__ __align__(16) float s_dfT[208][20];   // fp32 deter carry, transposed
    __shared__ __align__(16) float s_epT[208][20];   // Epre staged, transposed
    __shared__ __align__(16) float s_q[RB][64];
    __shared__ __align__(16) float s_bi[208];
    __shared__ __align__(16) float s_bq2[64];

    const int tid  = threadIdx.x;
    const int wv   = tid >> 6, ln = tid & 63;
    const int arow = ln & 15, kgrp = ln >> 4;
    const int b0   = blockIdx.x * RB;

    { u32* z = (u32*)s_in0; for (int i = tid; i < RB*72/2;   i += 512) z[i] = 0; }
    { u32* z = (u32*)s_x;   for (int i = tid; i < RB*SX/2;   i += 512) z[i] = 0; }
    { u32* z = (u32*)s_db;  for (int i = tid; i < 2*RB*SX/2; i += 512) z[i] = 0; }
    { u32* z = (u32*)s_hq;  for (int i = tid; i < RB*SX/2;   i += 512) z[i] = 0; }
    { float* z = (float*)s_dfT; for (int i = tid; i < 208*20; i += 512) z[i] = 0.f; }
    { float* z = (float*)s_epT; for (int i = tid; i < 208*20; i += 512) z[i] = 0.f; }
    for (int i = tid; i < 208; i += 512) s_bi[i] = (i < 200) ? bi[i] : 0.f;
    if (tid < 64) s_bq2[tid] = (tid < 60) ? bq2[tid] : 0.f;

    // wave-owned phase-B tiles + biases (loaded once)
    const int t0 = wv, t1 = wv + 8;
    const bool has2 = (t1 < 13);
    const int j0 = t0 * 16 + arow;
    const int j1 = t1 * 16 + arow;
    float bih0[3], bhh0[3], bih1[3], bhh1[3];
    #pragma unroll
    for (int g = 0; g < 3; ++g) {
        bih0[g] = (j0 < 200) ? b_ih[g * 200 + j0] : 0.f;
        bhh0[g] = (j0 < 200) ? b_hh[g * 200 + j0] : 0.f;
        bih1[g] = (has2 && j1 < 200) ? b_ih[g * 200 + j1] : 0.f;
        bhh1[g] = (has2 && j1 < 200) ? b_hh[g * 200 + j1] : 0.f;
    }
    __syncthreads();

    // prologue: stage Epre(0) + action(0)
    for (int idx = tid; idx < RB * 200; idx += 512) {
        int i = idx / 200, j = idx - i * 200;
        s_epT[j][i] = out[((size_t)(b0 + i) * NT + 0) * OC + 290 + j];
    }
    if (tid < RB * 6) {
        int i = tid / 6, c = tid - i * 6;
        s_in0[i][30 + c] = f2b(action[((size_t)(b0 + i) * NT + 0) * 6 + c]);
    }
    __syncthreads();

    int cur = 0;
    for (int t = 0; t < NT; ++t) {
        // ---- phase A: x = elu([stoch|act] @ Wi^T + bi) ----
        for (int tt = wv; tt < 13; tt += 8) {
            const float bv = s_bi[tt * 16 + arow];
            f32x4 acc = {bv, bv, bv, bv};
            #pragma unroll
            for (int ks = 0; ks < 2; ++ks) {
                short8 af = *(const short8*)&s_in0[arow][ks * 32 + kgrp * 8];
                short8 wf = *(const short8*)&wp[P_WI + (size_t)(tt * 2 + ks) * 1024 + ln * 8];
                acc = MFMA(af, wf, acc);
            }
            #pragma unroll
            for (int e = 0; e < 4; ++e)
                s_x[kgrp * 4 + e][tt * 16 + arow] = f2b(elu_f(acc[e]));
        }
        __syncthreads();

        // ---- phase B: GRU gates + in-register combine ----
        {
            f32x4 gi0[3], gh0[3], gi1[3], gh1[3];
            #pragma unroll
            for (int g = 0; g < 3; ++g) {
                gi0[g] = (f32x4){bih0[g], bih0[g], bih0[g], bih0[g]};
                gh0[g] = (f32x4){bhh0[g], bhh0[g], bhh0[g], bhh0[g]};
                gi1[g] = (f32x4){bih1[g], bih1[g], bih1[g], bih1[g]};
                gh1[g] = (f32x4){bhh1[g], bhh1[g], bhh1[g], bhh1[g]};
            }
            for (int ks = 0; ks < 7; ++ks) {
                short8 ax = *(const short8*)&s_x[arow][ks * 32 + kgrp * 8];
                short8 ad = *(const short8*)&s_db[cur][arow][ks * 32 + kgrp * 8];
                #pragma unroll
                for (int g = 0; g < 3; ++g) {
                    gi0[g] = MFMA(ax, *(const short8*)&wp[P_WIH + ((size_t)(g*13 + t0)*7 + ks)*1024 + ln*8], gi0[g]);
                    gh0[g] = MFMA(ad, *(const short8*)&wp[P_WHH + ((size_t)(g*13 + t0)*7 + ks)*1024 + ln*8], gh0[g]);
                }
                if (has2) {
                    #pragma unroll
                    for (int g = 0; g < 3; ++g) {
                        gi1[g] = MFMA(ax, *(const short8*)&wp[P_WIH + ((size_t)(g*13 + t1)*7 + ks)*1024 + ln*8], gi1[g]);
                        gh1[g] = MFMA(ad, *(const short8*)&wp[P_WHH + ((size_t)(g*13 + t1)*7 + ks)*1024 + ln*8], gh1[g]);
                    }
                }
            }
            {   // combine tile 0
                float4 dp = *(const float4*)&s_dfT[j0][kgrp * 4];
                float dn[4];
                const float dpv[4] = {dp.x, dp.y, dp.z, dp.w};
                #pragma unroll
                for (int e = 0; e < 4; ++e) {
                    float rr = sig_f(gi0[0][e] + gh0[0][e]);
                    float zz = sig_f(gi0[1][e] + gh0[1][e]);
                    float nn = tanhf(gi0[2][e] + rr * gh0[2][e]);
                    dn[e] = (1.f - zz) * nn + zz * dpv[e];
                }
                float4 dnv; dnv.x = dn[0]; dnv.y = dn[1]; dnv.z = dn[2]; dnv.w = dn[3];
                *(float4*)&s_dfT[j0][kgrp * 4] = dnv;
                #pragma unroll
                for (int e = 0; e < 4; ++e) s_db[cur ^ 1][kgrp * 4 + e][j0] = f2b(dn[e]);
            }
            if (has2) {   // combine tile 1
                float4 dp = *(const float4*)&s_dfT[j1][kgrp * 4];
                float dn[4];
                const float dpv[4] = {dp.x, dp.y, dp.z, dp.w};
                #pragma unroll
                for (int e = 0; e < 4; ++e) {
                    float rr = sig_f(gi1[0][e] + gh1[0][e]);
                    float zz = sig_f(gi1[1][e] + gh1[1][e]);
                    float nn = tanhf(gi1[2][e] + rr * gh1[2][e]);
                    dn[e] = (1.f - zz) * nn + zz * dpv[e];
                }
                float4 dnv; dnv.x = dn[0]; dnv.y = dn[1]; dnv.z = dn[2]; dnv.w = dn[3];
                *(float4*)&s_dfT[j1][kgrp * 4] = dnv;
                #pragma unroll
                for (int e = 0; e < 4; ++e) s_db[cur ^ 1][kgrp * 4 + e][j1] = f2b(dn[e]);
            }
        }
        __syncthreads();

        // ---- phase C: hq = elu(deter_new @ Wq1a^T + Epre) ----
        for (int tt = wv; tt < 13; tt += 8) {
            const int j = tt * 16 + arow;
            float4 ep = *(const float4*)&s_epT[j][kgrp * 4];
            f32x4 acc = {ep.x, ep.y, ep.z, ep.w};
            #pragma unroll
            for (int ks = 0; ks < 7; ++ks) {
                short8 ad = *(const short8*)&s_db[cur ^ 1][arow][ks * 32 + kgrp * 8];
                short8 wf = *(const short8*)&wp[P_WQ1 + ((size_t)tt * 7 + ks) * 1024 + ln * 8];
                acc = MFMA(ad, wf, acc);
            }
            #pragma unroll
            for (int e = 0; e < 4; ++e)
                s_hq[kgrp * 4 + e][j] = f2b(elu_f(acc[e]));
        }
        __syncthreads();

        // ---- phase D1: q = hq @ Wq2^T + bq2 ----
        if (wv < 4) {
            const int tt = wv, j = tt * 16 + arow;
            const float bv = s_bq2[j];
            f32x4 acc = {bv, bv, bv, bv};
            #pragma unroll
            for (int ks = 0; ks < 7; ++ks) {
                short8 ah = *(const short8*)&s_hq[arow][ks * 32 + kgrp * 8];
                short8 wf = *(const short8*)&wp[P_WQ2 + ((size_t)tt * 7 + ks) * 1024 + ln * 8];
                acc = MFMA(ah, wf, acc);
            }
            #pragma unroll
            for (int e = 0; e < 4; ++e) s_q[kgrp * 4 + e][j] = acc[e];
        }
        __syncthreads();

        // ---- D2: sample + all global writes + stage(t+1) ----
        if (tid < RB * 30) {
            int i = tid / 30, s = tid - i * 30;
            float qm = s_q[i][s];
            float qs = sp_f(s_q[i][30 + s]) + 0.1f;
            size_t bt = (size_t)(b0 + i) * NT + t;
            float qst = noise_post[bt * 30 + s] * qs + qm;
            size_t o = bt * OC;
            out[o + s]      = qm;
            out[o + 30 + s] = qs;
            out[o + 60 + s] = qst;
            s_in0[i][s] = f2b(qst);
        }
        for (int idx = tid; idx < RB * 200; idx += 512) {
            int i = idx / 200, j = idx - i * 200;
            float d = s_dfT[j][i];
            size_t o = ((size_t)(b0 + i) * NT + t) * OC;
            out[o + 90 + j]  = d;
            out[o + 380 + j] = d;
        }
        if (t + 1 < NT) {
            for (int idx = tid; idx < RB * 200; idx += 512) {
                int i = idx / 200, j = idx - i * 200;
                s_epT[j][i] = out[((size_t)(b0 + i) * NT + (t + 1)) * OC + 290 + j];
            }
            if (tid < RB * 6) {
                int i = tid / 6, c = tid - i * 6;
                s_in0[i][30 + c] = f2b(action[((size_t)(b0 + i) * NT + (t + 1)) * 6 + c]);
            }
        }
        __syncthreads();
        cur ^= 1;
    }
}

// ---------------------------------------------------------------------------
// Prior head (MFMA): 1024 blocks x 64 bt-rows, 256 thr (4 waves x 16 rows).
// ---------------------------------------------------------------------------
__global__ __launch_bounds__(256) void prior_mfma(
    const float* __restrict__ noise_prior, const u16* __restrict__ wp,
    const float* __restrict__ bp1, const float* __restrict__ bp2,
    float* __restrict__ out)
{
    __shared__ __align__(16) u16   s_hp[64][SX];
    __shared__ __align__(16) float s_p[64][68];
    const int tid = threadIdx.x;
    const int wv = tid >> 6, ln = tid & 63;
    const int arow = ln & 15, kgrp = ln >> 4;
    const size_t bt0 = (size_t)blockIdx.x * 64;
    const int m0 = wv * 16;

    for (int idx = tid; idx < 64 * 32; idx += 256) {   // zero pad cols 200..231
        int r2 = idx >> 5, c = 200 + (idx & 31);
        s_hp[r2][c] = 0;
    }

    // GEMM1: hp = elu(deter @ Wp1^T + bp1)
    f32x4 acc[13];
    #pragma unroll
    for (int tt = 0; tt < 13; ++tt) {
        const int j = tt * 16 + arow;
        const float bv = (j < 200) ? bp1[j] : 0.f;
        acc[tt] = (f32x4){bv, bv, bv, bv};
    }
    for (int ks = 0; ks < 7; ++ks) {
        short8 a;
        const int k0 = ks * 32 + kgrp * 8;
        if (k0 <= 192) {
            const float* dp = &out[(bt0 + m0 + arow) * OC + 380 + k0];
            float4 v0 = *(const float4*)dp;
            float4 v1 = *(const float4*)(dp + 4);
            a = pack8(v0, v1);
        } else {
            a = (short8){0, 0, 0, 0, 0, 0, 0, 0};
        }
        const u16* bp = &wp[P_WP1 + (size_t)ks * 13 * 1024 + (size_t)ln * 8];
        #pragma unroll
        for (int tt = 0; tt < 13; ++tt)
            acc[tt] = MFMA(a, *(const short8*)(bp + (size_t)tt * 1024), acc[tt]);
    }
    #pragma unroll
    for (int tt = 0; tt < 13; ++tt)
        #pragma unroll
        for (int e = 0; e < 4; ++e)
            s_hp[m0 + kgrp * 4 + e][tt * 16 + (ln & 15)] = f2b(elu_f(acc[tt][e]));
    __syncthreads();

    // GEMM2: p = hp @ Wp2^T + bp2
    f32x4 acc2[4];
    #pragma unroll
    for (int tt = 0; tt < 4; ++tt) {
        const int j = tt * 16 + arow;
        const float bv = (j < 60) ? bp2[j] : 0.f;
        acc2[tt] = (f32x4){bv, bv, bv, bv};
    }
    #pragma unroll
    for (int ks = 0; ks < 7; ++ks) {
        short8 ah = *(const short8*)&s_hp[m0 + arow][ks * 32 + kgrp * 8];
        const u16* bp = &wp[P_WP2 + (size_t)ks * 4 * 1024 + (size_t)ln * 8];
        #pragma unroll
        for (int tt = 0; tt < 4; ++tt)
            acc2[tt] = MFMA(ah, *(const short8*)(bp + (size_t)tt * 1024), acc2[tt]);
    }
    #pragma unroll
    for (int tt = 0; tt < 4; ++tt)
        #pragma unroll
        for (int e = 0; e < 4; ++e)
            s_p[m0 + kgrp * 4 + e][tt * 16 + (ln & 15)] = acc2[tt][e];
    __syncthreads();

    // sample + store
    for (int idx = tid; idx < 64 * 30; idx += 256) {
        int i = idx / 30, s = idx - i * 30;
        float pm = s_p[i][s];
        float ps = sp_f(s_p[i][30 + s]) + 0.1f;
        float pst = noise_prior[(bt0 + i) * 30 + s] * ps + pm;
        size_t base = (bt0 + i) * OC;
        out[base + 290 + s] = pm;
        out[base + 320 + s] = ps;
        out[base + 350 + s] = pst;
    }
}

extern "C" void kernel_launch(void* const* d_in, const int* in_sizes, int n_in,
                              void* d_out, int out_size, void* d_ws, size_t ws_size,
                              hipStream_t stream)
{
    (void)in_sizes; (void)n_in; (void)out_size; (void)ws_size;
    const float* embed       = (const float*)d_in[0];
    const float* action      = (const float*)d_in[1];
    const float* noise_prior = (const float*)d_in[2];
    const float* noise_post  = (const float*)d_in[3];
    const float* Wi   = (const float*)d_in[4];
    const float* bi   = (const float*)d_in[5];
    const float* W_ih = (const float*)d_in[6];
    const float* W_hh = (const float*)d_in[7];
    const float* b_ih = (const float*)d_in[8];
    const float* b_hh = (const float*)d_in[9];
    const float* Wp1  = (const float*)d_in[10];
    const float* bp1  = (const float*)d_in[11];
    const float* Wp2  = (const float*)d_in[12];
    const float* bp2  = (const float*)d_in[13];
    const float* Wq1  = (const float*)d_in[14];
    const float* bq1  = (const float*)d_in[15];
    const float* Wq2  = (const float*)d_in[16];
    const float* bq2  = (const float*)d_in[17];
    float* out = (float*)d_out;
    u16* wp = (u16*)d_ws;

    hipLaunchKernelGGL(prep_pack, dim3((P_TOTAL + 255) / 256), dim3(256), 0, stream,
                       Wi, W_ih, W_hh, Wq1, Wq2, Wp1, Wp2, wp);
    hipLaunchKernelGGL(epre_mfma, dim3(256), dim3(512), 0, stream,
                       embed, wp, bq1, out);
    hipLaunchKernelGGL(scan_mfma, dim3(64), dim3(512), 0, stream,
                       action, noise_post, b_ih, b_hh, bi, bq2, wp, out);
    hipLaunchKernelGGL(prior_mfma, dim3(1024), dim3(256), 0, stream,
                       noise_prior, wp, bp1, bp2, out);
}